// Round 3
// baseline (539.316 us; speedup 1.0000x reference)
//
#include <hip/hip_runtime.h>

#define GAMMA 0.99f
#define BETA  0.01f
#define NB 8          // batches per wave, contiguous
#define WPB 4         // waves per 256-thread block

// Problem shape (fixed): B=65536, T=128, A=8.
// Persistent-style: 2048 blocks x 4 waves; each wave owns NB=8 contiguous
// batch rows and pipelines them 2-deep (load batch i+1 while computing i).
// Within a batch: lane l owns timesteps t0=2l, t1=2l+1 for the affine-scan;
// lp/ent are loaded fully coalesced (lane l -> float4 index l+64k) and gae
// weights redistributed with shuffles after the scan.

struct BatchRegs {
    float2 v2, r2;
    float  lv;
    int    tm;
    float4 L0, L1, L2, L3;
    float4 E0, E1, E2, E3;
};

__device__ __forceinline__ void load_batch(
    const float* __restrict__ values, const float* __restrict__ last_value,
    const float* __restrict__ rewards, const float* __restrict__ log_probs,
    const float* __restrict__ entropies, const int* __restrict__ terminal_mask,
    int b, int lane, BatchRegs& S)
{
    S.v2 = reinterpret_cast<const float2*>(values  + (size_t)b * 128)[lane];
    S.r2 = reinterpret_cast<const float2*>(rewards + (size_t)b * 128)[lane];
    S.lv = last_value[b];
    S.tm = terminal_mask[b];
    const float4* lp4 = reinterpret_cast<const float4*>(log_probs + (size_t)b * 1024);
    const float4* en4 = reinterpret_cast<const float4*>(entropies + (size_t)b * 1024);
    S.L0 = lp4[lane      ]; S.L1 = lp4[lane +  64];
    S.L2 = lp4[lane + 128]; S.L3 = lp4[lane + 192];
    S.E0 = en4[lane      ]; S.E1 = en4[lane +  64];
    S.E2 = en4[lane + 128]; S.E3 = en4[lane + 192];
}

__device__ __forceinline__ void compute_store(
    const BatchRegs& S, int lane, int b, float* __restrict__ out)
{
    const float v0 = S.v2.x, v1 = S.v2.y;
    const float r0 = S.r2.x, r1 = S.r2.y;
    const float R0 = (S.tm != 0) ? 0.0f : S.lv;

    // v_next at t1 = lane (l+1)'s v0; lane 63 -> R0
    float vnext1 = __shfl_down(v0, 1, 64);
    if (lane == 63) vnext1 = R0;
    const float delta1 = r1 + GAMMA * vnext1 - v1;
    const float delta0 = r0 + GAMMA * v1    - v0;

    // per-lane affine segment maps over (t1 then t0)
    float m  = GAMMA * GAMMA;
    float cR = fmaf(GAMMA, r1, r0);
    float cG = fmaf(GAMMA, delta1, delta0);

    // inclusive suffix scan of map composition
    #pragma unroll
    for (int d = 1; d < 64; d <<= 1) {
        const float om  = __shfl_down(m,  d, 64);
        const float ocR = __shfl_down(cR, d, 64);
        const float ocG = __shfl_down(cG, d, 64);
        if (lane + d < 64) {
            cR = fmaf(m, ocR, cR);
            cG = fmaf(m, ocG, cG);
            m  = m * om;
        }
    }
    // exclusive suffix (incoming carry); lane 63 gets identity
    float pm  = __shfl_down(m,  1, 64);
    float pcR = __shfl_down(cR, 1, 64);
    float pcG = __shfl_down(cG, 1, 64);
    if (lane == 63) { pm = 1.0f; pcR = 0.0f; pcG = 0.0f; }

    const float Rin = fmaf(pm, R0, pcR);
    const float gin = pcG;

    const float R1   = fmaf(GAMMA, Rin, r1);
    const float Rt0  = fmaf(GAMMA, R1,  r0);
    const float adv1 = R1  - v1;
    const float adv0 = Rt0 - v0;
    float critic = 0.5f * (adv1 * adv1 + adv0 * adv0);

    const float g1 = fmaf(GAMMA, gin, delta1);  // gae at t=2l+1
    const float g0 = fmaf(GAMMA, g1,  delta0);  // gae at t=2l

    // redistribute gae to the coalesced-lp layout:
    // float4 j = lane+64k covers t=j>>1, holder lane (lane>>2)+16k,
    // parity (lane>>1)&1 selects g0 (even t) vs g1 (odd t)
    const int par = (lane >> 1) & 1;
    const int hb  = lane >> 2;
    const float gA0 = __shfl(g0, hb,      64), gB0 = __shfl(g1, hb,      64);
    const float gA1 = __shfl(g0, hb + 16, 64), gB1 = __shfl(g1, hb + 16, 64);
    const float gA2 = __shfl(g0, hb + 32, 64), gB2 = __shfl(g1, hb + 32, 64);
    const float gA3 = __shfl(g0, hb + 48, 64), gB3 = __shfl(g1, hb + 48, 64);
    const float gk0 = par ? gB0 : gA0;
    const float gk1 = par ? gB1 : gA1;
    const float gk2 = par ? gB2 : gA2;
    const float gk3 = par ? gB3 : gA3;
    const float sL0 = (S.L0.x + S.L0.y) + (S.L0.z + S.L0.w);
    const float sL1 = (S.L1.x + S.L1.y) + (S.L1.z + S.L1.w);
    const float sL2 = (S.L2.x + S.L2.y) + (S.L2.z + S.L2.w);
    const float sL3 = (S.L3.x + S.L3.y) + (S.L3.z + S.L3.w);
    float actor = -(sL0 * gk0 + sL1 * gk1 + sL2 * gk2 + sL3 * gk3);

    const float esum =
          ((S.E0.x + S.E0.y) + (S.E0.z + S.E0.w)) + ((S.E1.x + S.E1.y) + (S.E1.z + S.E1.w))
        + ((S.E2.x + S.E2.y) + (S.E2.z + S.E2.w)) + ((S.E3.x + S.E3.y) + (S.E3.z + S.E3.w));
    actor = fmaf(-BETA, esum, actor);

    #pragma unroll
    for (int d = 32; d >= 1; d >>= 1) {
        actor  += __shfl_down(actor,  d, 64);
        critic += __shfl_down(critic, d, 64);
    }
    if (lane == 0) {
        reinterpret_cast<float2*>(out)[b] = make_float2(actor, critic);
    }
}

__global__ __launch_bounds__(256, 4) void a3c_loss_kernel(
    const float* __restrict__ values,
    const float* __restrict__ last_value,
    const float* __restrict__ rewards,
    const float* __restrict__ log_probs,
    const float* __restrict__ entropies,
    const int*   __restrict__ terminal_mask,
    float* __restrict__ out,
    int B)
{
    const int wave = threadIdx.x >> 6;
    const int lane = threadIdx.x & 63;
    const int b0 = (blockIdx.x * WPB + wave) * NB;   // contiguous chunk per wave
    if (b0 >= B) return;

    BatchRegs Ra, Rb;
    load_batch(values, last_value, rewards, log_probs, entropies, terminal_mask,
               b0, lane, Ra);

    #pragma unroll
    for (int i = 0; i < NB; i += 2) {
        const int bi = b0 + i;
        if (i + 1 < NB && bi + 1 < B)
            load_batch(values, last_value, rewards, log_probs, entropies,
                       terminal_mask, bi + 1, lane, Rb);
        compute_store(Ra, lane, bi, out);
        if (i + 1 < NB && bi + 1 < B) {
            if (i + 2 < NB && bi + 2 < B)
                load_batch(values, last_value, rewards, log_probs, entropies,
                           terminal_mask, bi + 2, lane, Ra);
            compute_store(Rb, lane, bi + 1, out);
        }
    }
}

extern "C" void kernel_launch(void* const* d_in, const int* in_sizes, int n_in,
                              void* d_out, int out_size, void* d_ws, size_t ws_size,
                              hipStream_t stream) {
    const float* values      = (const float*)d_in[0];
    const float* last_value  = (const float*)d_in[1];
    const float* rewards     = (const float*)d_in[2];
    const float* log_probs   = (const float*)d_in[3];
    const float* entropies   = (const float*)d_in[4];
    const int*   terminal    = (const int*)d_in[5];
    float* out = (float*)d_out;

    const int B = in_sizes[1];                        // 65536
    const int blocks = (B + WPB * NB - 1) / (WPB * NB);  // 2048

    a3c_loss_kernel<<<blocks, 256, 0, stream>>>(
        values, last_value, rewards, log_probs, entropies, terminal, out, B);
}